// Round 1
// baseline (40900.043 us; speedup 1.0000x reference)
//
#include <hip/hip_runtime.h>
#include <stdint.h>
#include <math.h>

#define HD 1024
#define BB 8
#define LL 2048

typedef unsigned short u16;
typedef unsigned int u32;

using bf16x8 = __attribute__((ext_vector_type(8))) short;
using f32x4  = __attribute__((ext_vector_type(4))) float;

__device__ __forceinline__ u16 f2bf(float f) {
  u32 x = __float_as_uint(f);
  x += 0x7fffu + ((x >> 16) & 1u);
  return (u16)(x >> 16);
}
__device__ __forceinline__ float bf2f(u16 u) {
  return __uint_as_float(((u32)u) << 16);
}
__device__ __forceinline__ float lo2f(u32 w) { return __uint_as_float(w << 16); }
__device__ __forceinline__ float hi2f(u32 w) { return __uint_as_float(w & 0xffff0000u); }

__device__ __forceinline__ float dot8(uint4 w, float4 a, float4 b) {
  float r;
  r  = lo2f(w.x) * a.x;  r += hi2f(w.x) * a.y;
  r += lo2f(w.y) * a.z;  r += hi2f(w.y) * a.w;
  r += lo2f(w.z) * b.x;  r += hi2f(w.z) * b.y;
  r += lo2f(w.w) * b.z;  r += hi2f(w.w) * b.w;
  return r;
}

// ---------------- input LN: x [16384,1024] f32 -> xn bf16 ----------------
__global__ __launch_bounds__(256) void k_ln_x(const float* __restrict__ x,
    const float* __restrict__ g, const float* __restrict__ b,
    u16* __restrict__ xn) {
  int row = blockIdx.x;
  int t = threadIdx.x;
  const float4* xr = (const float4*)(x + (size_t)row * HD);
  float4 v = xr[t];
  float s = v.x + v.y + v.z + v.w;
  float ss = v.x * v.x + v.y * v.y + v.z * v.z + v.w * v.w;
#pragma unroll
  for (int off = 32; off; off >>= 1) { s += __shfl_down(s, off); ss += __shfl_down(ss, off); }
  __shared__ float red[8];
  if ((t & 63) == 0) { red[t >> 6] = s; red[4 + (t >> 6)] = ss; }
  __syncthreads();
  s = red[0] + red[1] + red[2] + red[3];
  ss = red[4] + red[5] + red[6] + red[7];
  float m = s * (1.0f / HD);
  float rstd = rsqrtf(ss * (1.0f / HD) - m * m + 1e-5f);
  float4 gv = ((const float4*)g)[t];
  float4 bv = ((const float4*)b)[t];
  ushort4 o;
  o.x = f2bf((v.x - m) * rstd * gv.x + bv.x);
  o.y = f2bf((v.y - m) * rstd * gv.y + bv.y);
  o.z = f2bf((v.z - m) * rstd * gv.z + bv.z);
  o.w = f2bf((v.w - m) * rstd * gv.w + bv.w);
  *(ushort4*)(xn + (size_t)row * HD + t * 4) = o;
}

// ---------------- output LN, in place on f32 rows ----------------
__global__ __launch_bounds__(256) void k_out_ln(float* __restrict__ y,
    const float* __restrict__ g, const float* __restrict__ b) {
  int row = blockIdx.x;
  int t = threadIdx.x;
  float4* yr = (float4*)(y + (size_t)row * HD);
  float4 v = yr[t];
  float s = v.x + v.y + v.z + v.w;
  float ss = v.x * v.x + v.y * v.y + v.z * v.z + v.w * v.w;
#pragma unroll
  for (int off = 32; off; off >>= 1) { s += __shfl_down(s, off); ss += __shfl_down(ss, off); }
  __shared__ float red[8];
  if ((t & 63) == 0) { red[t >> 6] = s; red[4 + (t >> 6)] = ss; }
  __syncthreads();
  s = red[0] + red[1] + red[2] + red[3];
  ss = red[4] + red[5] + red[6] + red[7];
  float m = s * (1.0f / HD);
  float rstd = rsqrtf(ss * (1.0f / HD) - m * m + 1e-5f);
  float4 gv = ((const float4*)g)[t];
  float4 bv = ((const float4*)b)[t];
  float4 o;
  o.x = (v.x - m) * rstd * gv.x + bv.x;
  o.y = (v.y - m) * rstd * gv.y + bv.y;
  o.z = (v.z - m) * rstd * gv.z + bv.z;
  o.w = (v.w - m) * rstd * gv.w + bv.w;
  yr[t] = o;
}

// ---------------- pack weights to bf16: win=[3][1024][1024] (cols :H),
//                  wrec=[3][1024][1024] (cols H:) ----------------
__global__ __launch_bounds__(256) void k_pack_w(const float* __restrict__ wz,
    const float* __restrict__ wr, const float* __restrict__ wh,
    u16* __restrict__ win, u16* __restrict__ wrec) {
  int gid = blockIdx.x;           // 0..3071
  int gate = gid >> 10, o = gid & 1023;
  const float* w = (gate == 0) ? wz : ((gate == 1) ? wr : wh);
  const float* row = w + (size_t)o * (2 * HD);
  int t = threadIdx.x;
  float4 a = ((const float4*)row)[t];
  float4 b = ((const float4*)(row + HD))[t];
  ushort4 ua, ub;
  ua.x = f2bf(a.x); ua.y = f2bf(a.y); ua.z = f2bf(a.z); ua.w = f2bf(a.w);
  ub.x = f2bf(b.x); ub.y = f2bf(b.y); ub.z = f2bf(b.z); ub.w = f2bf(b.w);
  *(ushort4*)(win  + (size_t)gid * HD + t * 4) = ua;
  *(ushort4*)(wrec + (size_t)gid * HD + t * 4) = ub;
}

// ---------------- bf16 MFMA GEMM: C[16384,3072] = A[16384,1024] * B[3072,1024]^T
__global__ __launch_bounds__(256) void k_gemm(const u16* __restrict__ A,
    const u16* __restrict__ Bw, u16* __restrict__ C) {
  __shared__ u16 As[128 * 32];
  __shared__ u16 Bs[128 * 32];
  int tid = threadIdx.x;
  int bx = blockIdx.x % 24;       // N tile
  int by = blockIdx.x / 24;       // M tile
  int m0 = by * 128, n0 = bx * 128;
  int lane = tid & 63, wave = tid >> 6;
  int wr = wave >> 1, wc = wave & 1;
  int rl = lane & 15, kq = (lane >> 4) * 8;
  f32x4 acc[4][4] = {};
  int srow = tid >> 2, skb = (tid & 3) * 8;
  for (int k0 = 0; k0 < 1024; k0 += 32) {
    __syncthreads();
#pragma unroll
    for (int i = 0; i < 2; i++) {
      int row = srow + i * 64;
      uint4 av = *(const uint4*)(A + (size_t)(m0 + row) * 1024 + k0 + skb);
      *(uint4*)(As + row * 32 + skb) = av;
      uint4 bv = *(const uint4*)(Bw + (size_t)(n0 + row) * 1024 + k0 + skb);
      *(uint4*)(Bs + row * 32 + skb) = bv;
    }
    __syncthreads();
    bf16x8 af[4], bg[4];
#pragma unroll
    for (int mi = 0; mi < 4; mi++)
      af[mi] = *(const bf16x8*)(As + (wr * 64 + mi * 16 + rl) * 32 + kq);
#pragma unroll
    for (int ni = 0; ni < 4; ni++)
      bg[ni] = *(const bf16x8*)(Bs + (wc * 64 + ni * 16 + rl) * 32 + kq);
#pragma unroll
    for (int mi = 0; mi < 4; mi++)
#pragma unroll
      for (int ni = 0; ni < 4; ni++)
        acc[mi][ni] = __builtin_amdgcn_mfma_f32_16x16x32_bf16(af[mi], bg[ni], acc[mi][ni], 0, 0, 0);
  }
  int rowq = (lane >> 4) * 4;
#pragma unroll
  for (int mi = 0; mi < 4; mi++)
#pragma unroll
    for (int ni = 0; ni < 4; ni++)
#pragma unroll
      for (int r = 0; r < 4; r++) {
        int row = m0 + wr * 64 + mi * 16 + rowq + r;
        int col = n0 + wc * 64 + ni * 16 + rl;
        C[(size_t)row * 3072 + col] = f2bf(acc[mi][ni][r]);
      }
}

// ---------------- recurrence phase 1: hn = LN(h); z,r gates ----------------
// grid 128 blocks: blocks 0..63 -> z rows, 64..127 -> r rows, 16 rows each.
__global__ __launch_bounds__(256) void k_phase1(
    const float* __restrict__ hbuf, const u16* __restrict__ wrec,
    const u16* __restrict__ gx, const float* __restrict__ bz,
    const float* __restrict__ br, const float* __restrict__ g_st,
    const float* __restrict__ b_st, float* __restrict__ hn_out,
    float* __restrict__ zbuf, float* __restrict__ rbuf, int step) {
  __shared__ float hn_s[BB * HD];
  int t = threadIdx.x;
  int bb = t >> 5, l32 = t & 31;
  const float4* hr = (const float4*)(hbuf + bb * HD);
  float s = 0.f, ss = 0.f;
  float4 hv[8];
#pragma unroll
  for (int i = 0; i < 8; i++) {
    float4 v = hr[l32 + 32 * i]; hv[i] = v;
    s += v.x + v.y + v.z + v.w;
    ss += v.x * v.x + v.y * v.y + v.z * v.z + v.w * v.w;
  }
#pragma unroll
  for (int off = 16; off; off >>= 1) { s += __shfl_down(s, off, 32); ss += __shfl_down(ss, off, 32); }
  s = __shfl(s, 0, 32); ss = __shfl(ss, 0, 32);
  float m = s * (1.0f / HD);
  float rstd = rsqrtf(ss * (1.0f / HD) - m * m + 1e-5f);
#pragma unroll
  for (int i = 0; i < 8; i++) {
    int i4 = l32 + 32 * i;
    float4 gv = ((const float4*)g_st)[i4];
    float4 bv = ((const float4*)b_st)[i4];
    float4 o;
    o.x = (hv[i].x - m) * rstd * gv.x + bv.x;
    o.y = (hv[i].y - m) * rstd * gv.y + bv.y;
    o.z = (hv[i].z - m) * rstd * gv.z + bv.z;
    o.w = (hv[i].w - m) * rstd * gv.w + bv.w;
    ((float4*)hn_s)[bb * 256 + i4] = o;
  }
  __syncthreads();
  if (blockIdx.x < BB) {  // publish hn for phase2
    ((float4*)(hn_out + blockIdx.x * HD))[t] = ((float4*)hn_s)[blockIdx.x * 256 + t];
  }
  int gate = blockIdx.x >> 6;
  int obase = (blockIdx.x & 63) * 16;
  const u16* wg = wrec + (size_t)gate * HD * HD;
  const float* bias = gate ? br : bz;
  float* outb = gate ? rbuf : zbuf;
  const u16* gxrow = gx + ((size_t)bb * LL + step) * 3072 + gate * HD;
#pragma unroll
  for (int jg = 0; jg < 4; jg++) {
    int o0 = obase + jg * 4;
    const uint4* w0 = (const uint4*)(wg + (size_t)(o0 + 0) * HD);
    const uint4* w1 = (const uint4*)(wg + (size_t)(o0 + 1) * HD);
    const uint4* w2 = (const uint4*)(wg + (size_t)(o0 + 2) * HD);
    const uint4* w3 = (const uint4*)(wg + (size_t)(o0 + 3) * HD);
    float a0 = 0, a1 = 0, a2 = 0, a3 = 0;
#pragma unroll
    for (int i = 0; i < 4; i++) {
      int i4 = l32 + 32 * i;
      float4 ha = ((const float4*)hn_s)[bb * 256 + i4 * 2];
      float4 hb = ((const float4*)hn_s)[bb * 256 + i4 * 2 + 1];
      a0 += dot8(w0[i4], ha, hb);
      a1 += dot8(w1[i4], ha, hb);
      a2 += dot8(w2[i4], ha, hb);
      a3 += dot8(w3[i4], ha, hb);
    }
#pragma unroll
    for (int off = 16; off; off >>= 1) {
      a0 += __shfl_down(a0, off, 32);
      a1 += __shfl_down(a1, off, 32);
      a2 += __shfl_down(a2, off, 32);
      a3 += __shfl_down(a3, off, 32);
    }
    if (l32 == 0) {
      float p0 = bf2f(gxrow[o0 + 0]) + bias[o0 + 0] + a0;
      float p1 = bf2f(gxrow[o0 + 1]) + bias[o0 + 1] + a1;
      float p2 = bf2f(gxrow[o0 + 2]) + bias[o0 + 2] + a2;
      float p3 = bf2f(gxrow[o0 + 3]) + bias[o0 + 3] + a3;
      outb[bb * HD + o0 + 0] = 1.f / (1.f + expf(-p0));
      outb[bb * HD + o0 + 1] = 1.f / (1.f + expf(-p1));
      outb[bb * HD + o0 + 2] = 1.f / (1.f + expf(-p2));
      outb[bb * HD + o0 + 3] = 1.f / (1.f + expf(-p3));
    }
  }
}

// ---------------- recurrence phase 2: h_cand, h update ----------------
// grid 64 blocks, 16 h-rows each.
__global__ __launch_bounds__(256) void k_phase2(
    float* __restrict__ hbuf, const u16* __restrict__ wrec,
    const u16* __restrict__ gx, const float* __restrict__ bh,
    const float* __restrict__ hn_in, const float* __restrict__ zbuf,
    const float* __restrict__ rbuf, float* __restrict__ dout, int step) {
  __shared__ float u_s[BB * HD];
  int t = threadIdx.x;
#pragma unroll
  for (int i = 0; i < 8; i++) {
    int idx = t + 256 * i;
    float4 r4 = ((const float4*)rbuf)[idx];
    float4 n4 = ((const float4*)hn_in)[idx];
    float4 u;
    u.x = r4.x * n4.x; u.y = r4.y * n4.y; u.z = r4.z * n4.z; u.w = r4.w * n4.w;
    ((float4*)u_s)[idx] = u;
  }
  __syncthreads();
  int bb = t >> 5, l32 = t & 31;
  int obase = blockIdx.x * 16;
  const u16* wg = wrec + (size_t)2 * HD * HD;
  const u16* gxrow = gx + ((size_t)bb * LL + step) * 3072 + 2 * HD;
#pragma unroll
  for (int jg = 0; jg < 4; jg++) {
    int o0 = obase + jg * 4;
    const uint4* w0 = (const uint4*)(wg + (size_t)(o0 + 0) * HD);
    const uint4* w1 = (const uint4*)(wg + (size_t)(o0 + 1) * HD);
    const uint4* w2 = (const uint4*)(wg + (size_t)(o0 + 2) * HD);
    const uint4* w3 = (const uint4*)(wg + (size_t)(o0 + 3) * HD);
    float a0 = 0, a1 = 0, a2 = 0, a3 = 0;
#pragma unroll
    for (int i = 0; i < 4; i++) {
      int i4 = l32 + 32 * i;
      float4 ha = ((const float4*)u_s)[bb * 256 + i4 * 2];
      float4 hb = ((const float4*)u_s)[bb * 256 + i4 * 2 + 1];
      a0 += dot8(w0[i4], ha, hb);
      a1 += dot8(w1[i4], ha, hb);
      a2 += dot8(w2[i4], ha, hb);
      a3 += dot8(w3[i4], ha, hb);
    }
#pragma unroll
    for (int off = 16; off; off >>= 1) {
      a0 += __shfl_down(a0, off, 32);
      a1 += __shfl_down(a1, off, 32);
      a2 += __shfl_down(a2, off, 32);
      a3 += __shfl_down(a3, off, 32);
    }
    if (l32 == 0) {
      float accs[4] = {a0, a1, a2, a3};
#pragma unroll
      for (int rr = 0; rr < 4; rr++) {
        int o = o0 + rr;
        float p = bf2f(gxrow[o]) + bh[o] + accs[rr];
        float hc = tanhf(p);
        float z = zbuf[bb * HD + o];
        float ho = hbuf[bb * HD + o];
        float hnew = ho + z * (hc - ho);
        hbuf[bb * HD + o] = hnew;
        dout[((size_t)bb * LL + step) * HD + o] = hnew;
      }
    }
  }
}

__global__ __launch_bounds__(256) void k_copy(const float* __restrict__ src,
    float* __restrict__ dst, int n4) {
  int i = blockIdx.x * blockDim.x + threadIdx.x;
  if (i < n4) ((float4*)dst)[i] = ((const float4*)src)[i];
}

extern "C" void kernel_launch(void* const* d_in, const int* in_sizes, int n_in,
                              void* d_out, int out_size, void* d_ws, size_t ws_size,
                              hipStream_t stream) {
  (void)in_sizes; (void)n_in; (void)out_size; (void)ws_size;
  const float* x    = (const float*)d_in[0];
  const float* h0   = (const float*)d_in[1];
  const float* wz   = (const float*)d_in[2];
  const float* bz   = (const float*)d_in[3];
  const float* wr   = (const float*)d_in[4];
  const float* br   = (const float*)d_in[5];
  const float* wh   = (const float*)d_in[6];
  const float* bh   = (const float*)d_in[7];
  const float* g_in = (const float*)d_in[8];
  const float* b_in = (const float*)d_in[9];
  const float* g_st = (const float*)d_in[10];
  const float* b_st = (const float*)d_in[11];
  const float* g_out= (const float*)d_in[12];
  const float* b_out= (const float*)d_in[13];
  float* out = (float*)d_out;

  char* ws = (char*)d_ws;
  u16* xn    = (u16*)(ws);                       // 32 MB
  u16* win   = (u16*)(ws + 33554432ull);         // 6 MB
  u16* wrec  = (u16*)(ws + 39845888ull);         // 6 MB
  u16* gx    = (u16*)(ws + 46137344ull);         // 96 MB
  float* hbuf = (float*)(ws + 146800640ull);     // 32 KB
  float* hn   = (float*)(ws + 146833408ull);     // 32 KB
  float* zbuf = (float*)(ws + 146866176ull);     // 32 KB
  float* rbuf = (float*)(ws + 146898944ull);     // 32 KB

  k_pack_w<<<dim3(3072), dim3(256), 0, stream>>>(wz, wr, wh, win, wrec);
  k_ln_x<<<dim3(16384), dim3(256), 0, stream>>>(x, g_in, b_in, xn);
  k_gemm<<<dim3(3072), dim3(256), 0, stream>>>(xn, win, gx);
  hipMemcpyAsync(hbuf, h0, (size_t)BB * HD * sizeof(float),
                 hipMemcpyDeviceToDevice, stream);
  for (int step = 0; step < LL; step++) {
    k_phase1<<<dim3(128), dim3(256), 0, stream>>>(hbuf, wrec, gx, bz, br,
                                                  g_st, b_st, hn, zbuf, rbuf, step);
    k_phase2<<<dim3(64), dim3(256), 0, stream>>>(hbuf, wrec, gx, bh, hn,
                                                 zbuf, rbuf, out, step);
  }
  k_out_ln<<<dim3(16384), dim3(256), 0, stream>>>(out, g_out, b_out);
  k_copy<<<dim3(8), dim3(256), 0, stream>>>(hbuf, out + (size_t)16384 * 1024, 2048);
}